// Round 1
// 5693.773 us; speedup vs baseline: 1.3793x; 1.3793x over previous
//
#include <hip/hip_runtime.h>
#include <hip/hip_bf16.h>

// Sizes (fixed by the problem)
#define B_   64
#define T_   512
#define I_   512
#define H_   512
#define NBLK 128   // 64 blocks per layer; block owns 8 hidden units (32 gate cols)
#define NTHR 256   // 4 waves; wave w owns M-tile rows [16w, 16w+16)

typedef short bf16x8 __attribute__((ext_vector_type(8)));
typedef float f32x4  __attribute__((ext_vector_type(4)));
typedef unsigned long long u64;
typedef unsigned short u16;

#define MFMA(a, b, c) __builtin_amdgcn_mfma_f32_16x16x32_bf16((a), (b), (c), 0, 0, 0)

__device__ __forceinline__ u16 f2b(float f) {
    __hip_bfloat16 h = __float2bfloat16(f);   // RNE
    return __builtin_bit_cast(u16, h);
}

// Agent-scope (device-coherent, LLC-backed) 16B load from two u64 relaxed atomics.
__device__ __forceinline__ bf16x8 coh_ld8(const u16* p) {
    u64 lo = __hip_atomic_load((const u64*)p,     __ATOMIC_RELAXED, __HIP_MEMORY_SCOPE_AGENT);
    u64 hi = __hip_atomic_load((const u64*)p + 1, __ATOMIC_RELAXED, __HIP_MEMORY_SCOPE_AGENT);
    union { u64 q[2]; bf16x8 v; } u;
    u.q[0] = lo; u.q[1] = hi;
    return u.v;
}

// lane i checks block i's single flag.
__device__ __forceinline__ bool flag_ge(const int* f, int lane, int tgt) {
    return __hip_atomic_load(f + lane, __ATOMIC_RELAXED, __HIP_MEMORY_SCOPE_AGENT) >= tgt;
}

// Init: x fp32 -> bf16, initial h -> ring slot 7 (both layers), flags = 0.
__global__ void k_init(const float* __restrict__ x, const float* __restrict__ h,
                       u16* __restrict__ xb, u16* __restrict__ h0ring, u16* __restrict__ h1ring,
                       int* __restrict__ flags0, int* __restrict__ flags1) {
    long i = (long)blockIdx.x * 256 + threadIdx.x;
    if (i < 2097152) {                          // x: 16,777,216 floats, 8 per thread
        const float* p = x + i * 8;
        float4 a = *(const float4*)p;
        float4 b = *(const float4*)(p + 4);
        union { u16 s[8]; bf16x8 v; } u;
        u.s[0]=f2b(a.x); u.s[1]=f2b(a.y); u.s[2]=f2b(a.z); u.s[3]=f2b(a.w);
        u.s[4]=f2b(b.x); u.s[5]=f2b(b.y); u.s[6]=f2b(b.z); u.s[7]=f2b(b.w);
        *(bf16x8*)(xb + i * 8) = u.v;
    } else if (i < 2097152 + 8192) {            // h: [2][64][512] = 65536 floats
        long j = i - 2097152;
        const float* p = h + j * 8;
        #pragma unroll
        for (int jj = 0; jj < 8; ++jj) {
            long idx = j * 8 + jj;
            u16 v = f2b(p[jj]);
            if (idx < 32768) h0ring[7 * 32768 + idx] = v;
            else             h1ring[7 * 32768 + (idx - 32768)] = v;
        }
    } else if (i < 2097152 + 8192 + 512) {      // flags
        int j = (int)(i - (2097152 + 8192));
        if (j < 256) flags0[j] = 0; else flags1[j - 256] = 0;
    }
}

__global__ __launch_bounds__(NTHR, 1) void k_lstm(
    const u16* __restrict__ xb,
    const float* __restrict__ Wx0, const float* __restrict__ Wh0, const float* __restrict__ b0,
    const float* __restrict__ Wx1, const float* __restrict__ Wh1, const float* __restrict__ b1,
    const float* __restrict__ c_in,
    u16* __restrict__ h0ring, u16* __restrict__ h1ring,
    int* __restrict__ flags0, int* __restrict__ flags1,
    float* __restrict__ cs,
    float* __restrict__ out)
{
    const int tid  = threadIdx.x;
    const int bid  = blockIdx.x;
    const int lay  = bid >> 6;        // 0 or 1
    const int ub   = bid & 63;        // unit block: hidden units [ub*8, ub*8+8)
    const int wave = tid >> 6;        // M-tile index 0..3
    const int lane = tid & 63;
    const int n    = lane & 15;       // A row-in-tile / B col-in-tile
    const int quad = lane >> 4;

    // Early-phase (latency-tolerant) K-half of the weights lives in LDS; the
    // latency-critical K-half stays in registers so the post-flag phase is
    // pure {coherent loads -> MFMA} with ~380 free VGPRs for load pipelining.
    __shared__ __align__(16) bf16x8 wlds[2][16][64];   // 32 KiB
    __shared__ __align__(16) u16    sc_hb[4][16][8];   // per-wave h(bf16) transpose scratch
    __shared__ __align__(16) float  sc_h [4][16][8];   // per-wave h(f32) transpose scratch

    const float* Wx = lay ? Wx1 : Wx0;
    const float* Wh = lay ? Wh1 : Wh0;
    const float* bb = lay ? b1  : b0;
    const float bi = bb[0] + bb[1];
    const float bf = bb[2] + bb[3];
    const float bg = bb[4] + bb[5];
    const float bo = bb[6] + bb[7];

    // Register half = critical phase:  L0: K[512,1024)=Wh0 ;  L1: K[0,512)=Wx1 (h0 input)
    // LDS half      = early phase:     L0: K[0,512)  =Wx0 ;  L1: K[512,1024)=Wh1 (h1 input)
    const int kreg0 = lay ? 0 : 512;
    const int klds0 = lay ? 512 : 0;

    // B-frag layout (per frag f): lane holds B[k = base + quad*8 + j][col = ct*16 + n].
    bf16x8 breg[2][16];
    #pragma unroll
    for (int ct = 0; ct < 2; ++ct) {
        const int c    = ct * 16 + n;
        const int gcol = (c >> 3) * 512 + ub * 8 + (c & 7); // global gate column
        #pragma unroll
        for (int f = 0; f < 16; ++f) {
            const int kbase = kreg0 + f * 32 + quad * 8;
            bf16x8 w;
            #pragma unroll
            for (int j = 0; j < 8; ++j) {
                const int k = kbase + j;
                const float v = (k < 512) ? Wx[(size_t)k * 2048 + gcol]
                                          : Wh[(size_t)(k - 512) * 2048 + gcol];
                w[j] = (short)f2b(v);
            }
            breg[ct][f] = w;
        }
        // cooperative LDS half: wave w builds frags [4w, 4w+4)
        #pragma unroll
        for (int ff = 0; ff < 4; ++ff) {
            const int f = wave * 4 + ff;
            const int kbase = klds0 + f * 32 + quad * 8;
            bf16x8 w;
            #pragma unroll
            for (int j = 0; j < 8; ++j) {
                const int k = kbase + j;
                const float v = (k < 512) ? Wx[(size_t)k * 2048 + gcol]
                                          : Wh[(size_t)(k - 512) * 2048 + gcol];
                w[j] = (short)f2b(v);
            }
            wlds[ct][f][lane] = w;
        }
    }
    __syncthreads();

    const int mrow0 = wave * 16;
    const int arow  = mrow0 + n;            // A row this lane supplies
    int* myflag = (lay ? flags1 : flags0) + ub;
    (void)cs;

    // c-state lives in registers: lane (n<8, quad) owns rows quad*4+r, unit ub*8+n.
    float creg[4];
    if (n < 8) {
        #pragma unroll
        for (int r = 0; r < 4; ++r)
            creg[r] = c_in[(size_t)lay * 32768
                           + (size_t)(mrow0 + quad * 4 + r) * 512 + ub * 8 + n];
    }

    for (int t = 0; t < 512; ++t) {
        f32x4 acc0 = {0.f, 0.f, 0.f, 0.f};
        f32x4 acc1 = {0.f, 0.f, 0.f, 0.f};

        if (lay == 0) {
            // ---- x-phase: no cross-block dependency; overlaps producers' drain ----
            const u16* px = xb + ((size_t)arow * T_ + t) * I_;
            bf16x8 xa[16];
            #pragma unroll
            for (int f = 0; f < 16; ++f) xa[f] = *(const bf16x8*)(px + f * 32 + quad * 8);
            #pragma unroll
            for (int f = 0; f < 16; ++f) {
                acc0 = MFMA(xa[f], wlds[0][f][lane], acc0);
                acc1 = MFMA(xa[f], wlds[1][f][lane], acc1);
            }
            // ---- wait for h0[t-1]; ring WAR back-pressure only every 4th step ----
            // (check flags1 >= t-4 at t%4==0  =>  flags1 >= t'-7 for t' in [t, t+3])
            const bool bp = (t & 3) == 0;
            for (;;) {
                bool ok = flag_ge(flags0, lane, t);
                if (bp) ok = ok && flag_ge(flags1, lane, t - 4);
                if (__all(ok)) break;
                __builtin_amdgcn_s_sleep(1);
            }
            asm volatile("" ::: "memory");
            const u16* ph = h0ring + ((t - 1) & 7) * 32768 + (size_t)arow * H_;
            bf16x8 ha[16];
            #pragma unroll
            for (int f = 0; f < 16; ++f) ha[f] = coh_ld8(ph + f * 32 + quad * 8);
            #pragma unroll
            for (int f = 0; f < 16; ++f) {
                acc0 = MFMA(ha[f], breg[0][f], acc0);
                acc1 = MFMA(ha[f], breg[1][f], acc1);
            }
        } else {
            // ---- h1-phase (own layer; typically already published) ----
            while (!__all(flag_ge(flags1, lane, t))) __builtin_amdgcn_s_sleep(1);
            asm volatile("" ::: "memory");
            const u16* p1 = h1ring + ((t - 1) & 7) * 32768 + (size_t)arow * H_;
            bf16x8 h1a[16];
            #pragma unroll
            for (int f = 0; f < 16; ++f) h1a[f] = coh_ld8(p1 + f * 32 + quad * 8);
            #pragma unroll
            for (int f = 0; f < 16; ++f) {
                acc0 = MFMA(h1a[f], wlds[0][f][lane], acc0);
                acc1 = MFMA(h1a[f], wlds[1][f][lane], acc1);
            }
            // ---- h0-phase (fresh cross-layer dependency) ----
            while (!__all(flag_ge(flags0, lane, t + 1))) __builtin_amdgcn_s_sleep(1);
            asm volatile("" ::: "memory");
            const u16* p0 = h0ring + (t & 7) * 32768 + (size_t)arow * H_;
            bf16x8 h0a[16];
            #pragma unroll
            for (int f = 0; f < 16; ++f) h0a[f] = coh_ld8(p0 + f * 32 + quad * 8);
            #pragma unroll
            for (int f = 0; f < 16; ++f) {
                acc0 = MFMA(h0a[f], breg[0][f], acc0);
                acc1 = MFMA(h0a[f], breg[1][f], acc1);
            }
        }

        // D layout: col = lane&15, row = quad*4 + reg.
        // acc0 cols: n<8 -> gate i (unit n), n>=8 -> gate f (unit n-8)
        // acc1 cols: n<8 -> gate g,          n>=8 -> gate o
        f32x4 x0, x1;
        #pragma unroll
        for (int r = 0; r < 4; ++r) {
            x0[r] = __shfl_xor(acc0[r], 8);   // lane n gets zf
            x1[r] = __shfl_xor(acc1[r], 8);   // lane n gets zo
        }
        if (n < 8) {
            #pragma unroll
            for (int r = 0; r < 4; ++r) {
                const int row = quad * 4 + r;
                const float zi = acc0[r] + bi;
                const float zf = x0[r]   + bf;
                const float zg = acc1[r] + bg;
                const float zo = x1[r]   + bo;
                const float ig = 1.f / (1.f + __expf(-zi));
                const float fg = 1.f / (1.f + __expf(-zf));
                const float gg = tanhf(zg);
                const float og = 1.f / (1.f + __expf(-zo));
                const float cn = fg * creg[r] + ig * gg;
                const float hn = og * tanhf(cn);
                creg[r] = cn;
                sc_hb[wave][row][n] = f2b(hn);
                sc_h [wave][row][n] = hn;
            }
        }
        asm volatile("s_waitcnt lgkmcnt(0)" ::: "memory");  // transpose scratch ready

        // ---- packed h-ring publish: lane r<16 stores one 16B row as 2 u64 ----
        if (lane < 16) {
            const u64* s = (const u64*)&sc_hb[wave][lane][0];
            u64 q0 = s[0], q1 = s[1];
            u64* d = (u64*)((lay ? h1ring : h0ring) + (size_t)(t & 7) * 32768
                            + (size_t)(mrow0 + lane) * H_ + ub * 8);
            __hip_atomic_store(d,     q0, __ATOMIC_RELAXED, __HIP_MEMORY_SCOPE_AGENT);
            __hip_atomic_store(d + 1, q1, __ATOMIC_RELAXED, __HIP_MEMORY_SCOPE_AGENT);
        }
        asm volatile("s_waitcnt vmcnt(0)" ::: "memory");  // h at coherence point
        __syncthreads();
        if (tid == 0)
            __hip_atomic_store(myflag, t + 1, __ATOMIC_RELAXED, __HIP_MEMORY_SCOPE_AGENT);

        // ---- off-critical-path outputs (drain folds into next step's waits) ----
        if (lay && lane < 16) {
            const float* s = &sc_h[wave][lane][0];
            f32x4 a  = *(const f32x4*)s;
            f32x4 b2 = *(const f32x4*)(s + 4);
            float* po = out + ((size_t)(mrow0 + lane) * T_ + t) * H_ + ub * 8;
            *(f32x4*)po       = a;
            *(f32x4*)(po + 4) = b2;
        }
        if (t == 511 && n < 8) {
            const size_t o1 = (size_t)B_ * T_ * H_;   // 16,777,216
            #pragma unroll
            for (int r = 0; r < 4; ++r) {
                const int grow = mrow0 + quad * 4 + r;
                out[o1 +         (size_t)lay * 32768 + (size_t)grow * 512 + ub * 8 + n]
                    = sc_h[wave][quad * 4 + r][n];
                out[o1 + 65536 + (size_t)lay * 32768 + (size_t)grow * 512 + ub * 8 + n]
                    = creg[r];
            }
        }
    }
}

extern "C" void kernel_launch(void* const* d_in, const int* in_sizes, int n_in,
                              void* d_out, int out_size, void* d_ws, size_t ws_size,
                              hipStream_t stream) {
    const float* x   = (const float*)d_in[0];
    const float* h   = (const float*)d_in[1];
    const float* c   = (const float*)d_in[2];
    const float* Wx0 = (const float*)d_in[3];
    const float* Wh0 = (const float*)d_in[4];
    const float* b0  = (const float*)d_in[5];
    const float* Wx1 = (const float*)d_in[6];
    const float* Wh1 = (const float*)d_in[7];
    const float* b1  = (const float*)d_in[8];
    float* out = (float*)d_out;

    // ws layout (~35 MB): xb bf16, h rings (depth 8, bf16), flags, c scratch (unused now).
    u16* xb     = (u16*)d_ws;                 // 16,777,216 u16
    u16* h0ring = xb + 16777216;              // 8*32768 u16
    u16* h1ring = h0ring + 262144;            // 8*32768 u16
    int* flags0 = (int*)(h1ring + 262144);    // 256 ints (only [0,64) used)
    int* flags1 = flags0 + 256;               // 256 ints (only [0,64) used)
    float* cs   = (float*)(flags1 + 256);     // 65536 f32 (unused)

    k_init<<<8226, 256, 0, stream>>>(x, h, xb, h0ring, h1ring, flags0, flags1);
    k_lstm<<<NBLK, NTHR, 0, stream>>>(xb, Wx0, Wh0, b0, Wx1, Wh1, b1, c,
                                      h0ring, h1ring, flags0, flags1, cs, out);
}

// Round 2
// 3588.078 us; speedup vs baseline: 2.1888x; 1.5869x over previous
//
#include <hip/hip_runtime.h>
#include <hip/hip_bf16.h>

// Sizes (fixed by the problem)
#define B_   64
#define T_   512
#define I_   512
#define H_   512
#define NBLK 128   // 2 layers x (4 row-groups x 16 unit-blocks); block: 16 rows x 32 units
#define NTHR 256   // 4 waves; wave w owns units [U0+8w, U0+8w+8), all 16 rows

typedef short bf16x8 __attribute__((ext_vector_type(8)));
typedef float f32x4  __attribute__((ext_vector_type(4)));
typedef unsigned long long u64;
typedef unsigned short u16;

#define MFMA(a, b, c) __builtin_amdgcn_mfma_f32_16x16x32_bf16((a), (b), (c), 0, 0, 0)

__device__ __forceinline__ u16 f2b(float f) {
    __hip_bfloat16 h = __float2bfloat16(f);   // RNE
    return __builtin_bit_cast(u16, h);
}

// Agent-scope (device-coherent, LLC-backed) 16B load from two u64 relaxed atomics.
__device__ __forceinline__ bf16x8 coh_ld8(const u16* p) {
    u64 lo = __hip_atomic_load((const u64*)p,     __ATOMIC_RELAXED, __HIP_MEMORY_SCOPE_AGENT);
    u64 hi = __hip_atomic_load((const u64*)p + 1, __ATOMIC_RELAXED, __HIP_MEMORY_SCOPE_AGENT);
    union { u64 q[2]; bf16x8 v; } u;
    u.q[0] = lo; u.q[1] = hi;
    return u.v;
}

__device__ __forceinline__ bool flag_ge(const int* f, int idx, int tgt) {
    return __hip_atomic_load(f + idx, __ATOMIC_RELAXED, __HIP_MEMORY_SCOPE_AGENT) >= tgt;
}

// Init: x fp32 -> bf16, initial h -> ring slot 7 (both layers), flags = 0.
__global__ void k_init(const float* __restrict__ x, const float* __restrict__ h,
                       u16* __restrict__ xb, u16* __restrict__ h0ring, u16* __restrict__ h1ring,
                       int* __restrict__ flags0, int* __restrict__ flags1) {
    long i = (long)blockIdx.x * 256 + threadIdx.x;
    if (i < 2097152) {                          // x: 16,777,216 floats, 8 per thread
        const float* p = x + i * 8;
        float4 a = *(const float4*)p;
        float4 b = *(const float4*)(p + 4);
        union { u16 s[8]; bf16x8 v; } u;
        u.s[0]=f2b(a.x); u.s[1]=f2b(a.y); u.s[2]=f2b(a.z); u.s[3]=f2b(a.w);
        u.s[4]=f2b(b.x); u.s[5]=f2b(b.y); u.s[6]=f2b(b.z); u.s[7]=f2b(b.w);
        *(bf16x8*)(xb + i * 8) = u.v;
    } else if (i < 2097152 + 8192) {            // h: [2][64][512] = 65536 floats
        long j = i - 2097152;
        const float* p = h + j * 8;
        #pragma unroll
        for (int jj = 0; jj < 8; ++jj) {
            long idx = j * 8 + jj;
            u16 v = f2b(p[jj]);
            if (idx < 32768) h0ring[7 * 32768 + idx] = v;
            else             h1ring[7 * 32768 + (idx - 32768)] = v;
        }
    } else if (i < 2097152 + 8192 + 512) {      // flags
        int j = (int)(i - (2097152 + 8192));
        if (j < 256) flags0[j] = 0; else flags1[j - 256] = 0;
    }
}

__global__ __launch_bounds__(NTHR, 1) void k_lstm(
    const u16* __restrict__ xb,
    const float* __restrict__ Wx0, const float* __restrict__ Wh0, const float* __restrict__ b0,
    const float* __restrict__ Wx1, const float* __restrict__ Wh1, const float* __restrict__ b1,
    const float* __restrict__ c_in,
    u16* __restrict__ h0ring, u16* __restrict__ h1ring,
    int* __restrict__ flags0, int* __restrict__ flags1,
    float* __restrict__ cs,
    float* __restrict__ out)
{
    const int tid  = threadIdx.x;
    const int bid  = blockIdx.x;
    const int lay  = bid >> 6;        // 0 or 1
    const int g    = (bid >> 4) & 3;  // row group: batch rows [16g, 16g+16)
    const int u    = bid & 15;        // unit block: hidden units [32u, 32u+32)
    const int wave = tid >> 6;
    const int lane = tid & 63;
    const int n    = lane & 15;       // A row-in-tile / B col-in-tile
    const int quad = lane >> 4;
    const int R0   = g * 16;
    const int U0   = u * 32;

    // h-slice staging (shared by all 4 waves): [buf][row][col], padded +8 u16/row
    // so that 16-row-strided ds_read_b128 hits 8 banks (2-way, free).
    __shared__ __align__(16) u16   hstage[2][16][520];   // ~33 KiB
    __shared__ __align__(16) u16   sc_hb[4][16][8];      // per-wave h(bf16) transpose scratch
    __shared__ __align__(16) float sc_h [4][16][8];      // per-wave h(f32) transpose scratch

    const float* Wx = lay ? Wx1 : Wx0;
    const float* Wh = lay ? Wh1 : Wh0;
    const float* bb = lay ? b1  : b0;
    const float bi = bb[0] + bb[1];
    const float bf = bb[2] + bb[3];
    const float bg = bb[4] + bb[5];
    const float bo = bb[6] + bb[7];

    // ---- Preload this wave's full weight panel into registers (64 frags, 256 VGPR).
    // breg[ct][f]: col-tile ct (cols = gate pair), K-window f*32..+32.
    // K = [0,512) from Wx (frags 0..15), [512,1024) from Wh (frags 16..31).
    // Frag layout: lane holds B[k = f*32 + quad*8 + j][col = ct*16 + n].
    bf16x8 breg[2][32];
    #pragma unroll
    for (int ct = 0; ct < 2; ++ct) {
        const int gate = ct * 2 + (n >> 3);            // 0:i 1:f 2:g 3:o
        const int gcol = gate * 512 + U0 + wave * 8 + (n & 7);
        #pragma unroll
        for (int f = 0; f < 32; ++f) {
            const int kbase = f * 32 + quad * 8;
            bf16x8 w;
            #pragma unroll
            for (int j = 0; j < 8; ++j) {
                const int k = kbase + j;
                const float v = (k < 512) ? Wx[(size_t)k * 2048 + gcol]
                                          : Wh[(size_t)(k - 512) * 2048 + gcol];
                w[j] = (short)f2b(v);
            }
            breg[ct][f] = w;
        }
    }

    int* myflag = (lay ? flags1 : flags0) + g * 16 + u;
    const int fidx = g * 16 + n;            // poll: only this row-group's 16 peers
    (void)cs;

    // c-state in registers: lane (n<8, quad) owns local rows quad*4+r, unit U0+wave*8+n.
    float creg[4];
    if (n < 8) {
        #pragma unroll
        for (int r = 0; r < 4; ++r)
            creg[r] = c_in[(size_t)lay * 32768
                           + (size_t)(R0 + quad * 4 + r) * 512 + U0 + wave * 8 + n];
    }

    // staging thread mapping: 64B (one cache line) per thread, conflict-free ds_write
    const int sr  = tid & 15;   // local row
    const int sch = tid >> 4;   // 32-col chunk

    for (int t = 0; t < 512; ++t) {
        f32x4 acc0 = {0.f, 0.f, 0.f, 0.f};
        f32x4 acc1 = {0.f, 0.f, 0.f, 0.f};

        if (lay == 0) {
            // ---- x-phase: no cross-block dependency; runs before the wait ----
            const u16* px = xb + ((size_t)(R0 + n) * T_ + t) * I_;
            bf16x8 xa[16];
            #pragma unroll
            for (int f = 0; f < 16; ++f) xa[f] = *(const bf16x8*)(px + f * 32 + quad * 8);
            #pragma unroll
            for (int f = 0; f < 16; ++f) {
                acc0 = MFMA(xa[f], breg[0][f], acc0);
                acc1 = MFMA(xa[f], breg[1][f], acc1);
            }
            // ---- wait for own row-group's h0[t-1]; ring WAR check every 4th step ----
            const bool bp = (t & 3) == 0;
            for (;;) {
                bool ok = flag_ge(flags0, fidx, t);
                if (bp) ok = ok && flag_ge(flags1, fidx, t - 4);
                if (__all(ok)) break;
                __builtin_amdgcn_s_sleep(1);
            }
            asm volatile("" ::: "memory");
            // ---- stage h0[t-1] row-slice (16 KB) once per block ----
            const u16* src = h0ring + (size_t)((t - 1) & 7) * 32768
                             + (size_t)(R0 + sr) * 512 + sch * 32;
            bf16x8 v0 = coh_ld8(src);
            bf16x8 v1 = coh_ld8(src + 8);
            bf16x8 v2 = coh_ld8(src + 16);
            bf16x8 v3 = coh_ld8(src + 24);
            *(bf16x8*)&hstage[0][sr][sch * 32]      = v0;
            *(bf16x8*)&hstage[0][sr][sch * 32 + 8]  = v1;
            *(bf16x8*)&hstage[0][sr][sch * 32 + 16] = v2;
            *(bf16x8*)&hstage[0][sr][sch * 32 + 24] = v3;
            __syncthreads();
            #pragma unroll
            for (int f = 0; f < 16; ++f) {
                bf16x8 ha = *(const bf16x8*)&hstage[0][n][f * 32 + quad * 8];
                acc0 = MFMA(ha, breg[0][16 + f], acc0);
                acc1 = MFMA(ha, breg[1][16 + f], acc1);
            }
        } else {
            // ---- wait for h1[t-1] (own layer) AND h0[t] (L0 runs ahead) together ----
            for (;;) {
                bool ok = flag_ge(flags1, fidx, t) && flag_ge(flags0, fidx, t + 1);
                if (__all(ok)) break;
                __builtin_amdgcn_s_sleep(1);
            }
            asm volatile("" ::: "memory");
            // ---- stage both slices in one round trip ----
            const u16* s0 = h0ring + (size_t)(t & 7) * 32768
                            + (size_t)(R0 + sr) * 512 + sch * 32;
            const u16* s1 = h1ring + (size_t)((t - 1) & 7) * 32768
                            + (size_t)(R0 + sr) * 512 + sch * 32;
            bf16x8 a0 = coh_ld8(s0);
            bf16x8 a1 = coh_ld8(s0 + 8);
            bf16x8 a2 = coh_ld8(s0 + 16);
            bf16x8 a3 = coh_ld8(s0 + 24);
            bf16x8 b0v = coh_ld8(s1);
            bf16x8 b1v = coh_ld8(s1 + 8);
            bf16x8 b2v = coh_ld8(s1 + 16);
            bf16x8 b3v = coh_ld8(s1 + 24);
            *(bf16x8*)&hstage[0][sr][sch * 32]      = a0;
            *(bf16x8*)&hstage[0][sr][sch * 32 + 8]  = a1;
            *(bf16x8*)&hstage[0][sr][sch * 32 + 16] = a2;
            *(bf16x8*)&hstage[0][sr][sch * 32 + 24] = a3;
            *(bf16x8*)&hstage[1][sr][sch * 32]      = b0v;
            *(bf16x8*)&hstage[1][sr][sch * 32 + 8]  = b1v;
            *(bf16x8*)&hstage[1][sr][sch * 32 + 16] = b2v;
            *(bf16x8*)&hstage[1][sr][sch * 32 + 24] = b3v;
            __syncthreads();
            #pragma unroll
            for (int f = 0; f < 16; ++f) {
                bf16x8 ha = *(const bf16x8*)&hstage[0][n][f * 32 + quad * 8];
                acc0 = MFMA(ha, breg[0][f], acc0);
                acc1 = MFMA(ha, breg[1][f], acc1);
            }
            #pragma unroll
            for (int f = 0; f < 16; ++f) {
                bf16x8 ha = *(const bf16x8*)&hstage[1][n][f * 32 + quad * 8];
                acc0 = MFMA(ha, breg[0][16 + f], acc0);
                acc1 = MFMA(ha, breg[1][16 + f], acc1);
            }
        }

        // D layout: col = lane&15, row = quad*4 + reg (local rows 0..15).
        // acc0 cols: n<8 -> gate i (unit n), n>=8 -> gate f (unit n-8)
        // acc1 cols: n<8 -> gate g,          n>=8 -> gate o
        f32x4 x0, x1;
        #pragma unroll
        for (int r = 0; r < 4; ++r) {
            x0[r] = __shfl_xor(acc0[r], 8);   // lane n gets zf
            x1[r] = __shfl_xor(acc1[r], 8);   // lane n gets zo
        }
        if (n < 8) {
            #pragma unroll
            for (int r = 0; r < 4; ++r) {
                const int row = quad * 4 + r;
                const float zi = acc0[r] + bi;
                const float zf = x0[r]   + bf;
                const float zg = acc1[r] + bg;
                const float zo = x1[r]   + bo;
                const float ig = 1.f / (1.f + __expf(-zi));
                const float fg = 1.f / (1.f + __expf(-zf));
                const float gg = tanhf(zg);
                const float og = 1.f / (1.f + __expf(-zo));
                const float cn = fg * creg[r] + ig * gg;
                const float hn = og * tanhf(cn);
                creg[r] = cn;
                sc_hb[wave][row][n] = f2b(hn);
                sc_h [wave][row][n] = hn;
            }
        }
        asm volatile("s_waitcnt lgkmcnt(0)" ::: "memory");  // transpose scratch ready

        // ---- packed h-ring publish: lane r<16 stores its row's 16B as 2 u64 ----
        if (lane < 16) {
            const u64* s = (const u64*)&sc_hb[wave][lane][0];
            u64 q0 = s[0], q1 = s[1];
            u64* d = (u64*)((lay ? h1ring : h0ring) + (size_t)(t & 7) * 32768
                            + (size_t)(R0 + lane) * 512 + U0 + wave * 8);
            __hip_atomic_store(d,     q0, __ATOMIC_RELAXED, __HIP_MEMORY_SCOPE_AGENT);
            __hip_atomic_store(d + 1, q1, __ATOMIC_RELAXED, __HIP_MEMORY_SCOPE_AGENT);
        }
        asm volatile("s_waitcnt vmcnt(0)" ::: "memory");  // h at coherence point
        __syncthreads();
        if (tid == 0)
            __hip_atomic_store(myflag, t + 1, __ATOMIC_RELAXED, __HIP_MEMORY_SCOPE_AGENT);

        // ---- off-critical-path outputs (drain folds into next step's waits) ----
        if (lay && lane < 16) {
            const float* s = &sc_h[wave][lane][0];
            f32x4 a  = *(const f32x4*)s;
            f32x4 b2 = *(const f32x4*)(s + 4);
            float* po = out + ((size_t)(R0 + lane) * T_ + t) * H_ + U0 + wave * 8;
            *(f32x4*)po       = a;
            *(f32x4*)(po + 4) = b2;
        }
        if (t == 511 && n < 8) {
            const size_t o1 = (size_t)B_ * T_ * H_;   // 16,777,216
            #pragma unroll
            for (int r = 0; r < 4; ++r) {
                const int grow = R0 + quad * 4 + r;
                out[o1 +         (size_t)lay * 32768 + (size_t)grow * 512 + U0 + wave * 8 + n]
                    = sc_h[wave][quad * 4 + r][n];
                out[o1 + 65536 + (size_t)lay * 32768 + (size_t)grow * 512 + U0 + wave * 8 + n]
                    = creg[r];
            }
        }
    }
}

extern "C" void kernel_launch(void* const* d_in, const int* in_sizes, int n_in,
                              void* d_out, int out_size, void* d_ws, size_t ws_size,
                              hipStream_t stream) {
    const float* x   = (const float*)d_in[0];
    const float* h   = (const float*)d_in[1];
    const float* c   = (const float*)d_in[2];
    const float* Wx0 = (const float*)d_in[3];
    const float* Wh0 = (const float*)d_in[4];
    const float* b0  = (const float*)d_in[5];
    const float* Wx1 = (const float*)d_in[6];
    const float* Wh1 = (const float*)d_in[7];
    const float* b1  = (const float*)d_in[8];
    float* out = (float*)d_out;

    // ws layout (~35 MB): xb bf16, h rings (depth 8, bf16), flags, spare.
    u16* xb     = (u16*)d_ws;                 // 16,777,216 u16
    u16* h0ring = xb + 16777216;              // 8*32768 u16
    u16* h1ring = h0ring + 262144;            // 8*32768 u16
    int* flags0 = (int*)(h1ring + 262144);    // 256 ints (only [0,64) used)
    int* flags1 = flags0 + 256;               // 256 ints (only [0,64) used)
    float* cs   = (float*)(flags1 + 256);     // spare (unused)

    k_init<<<8226, 256, 0, stream>>>(x, h, xb, h0ring, h1ring, flags0, flags1);
    k_lstm<<<NBLK, NTHR, 0, stream>>>(xb, Wx0, Wh0, b0, Wx1, Wh1, b1, c,
                                      h0ring, h1ring, flags0, flags1, cs, out);
}

// Round 4
// 3137.858 us; speedup vs baseline: 2.5028x; 1.1435x over previous
//
#include <hip/hip_runtime.h>
#include <hip/hip_bf16.h>

// Sizes (fixed by the problem)
#define B_   64
#define T_   512
#define I_   512
#define H_   512
#define NBLK 128   // 2 layers x (4 row-groups x 16 unit-blocks); block: 16 rows x 32 units
#define NTHR 256   // 4 waves; wave w owns units [U0+8w, U0+8w+8), all 16 rows

typedef short bf16x8 __attribute__((ext_vector_type(8)));
typedef float f32x4  __attribute__((ext_vector_type(4)));
typedef unsigned long long u64;
typedef unsigned short u16;

#define MFMA(a, b, c) __builtin_amdgcn_mfma_f32_16x16x32_bf16((a), (b), (c), 0, 0, 0)

__device__ __forceinline__ u16 f2b(float f) {
    __hip_bfloat16 h = __float2bfloat16(f);   // RNE
    return __builtin_bit_cast(u16, h);
}

// Agent-scope (device-coherent, LLC-backed) 8B load/store.
__device__ __forceinline__ u64 coh_ld64(const void* p) {
    return __hip_atomic_load((const u64*)p, __ATOMIC_RELAXED, __HIP_MEMORY_SCOPE_AGENT);
}
__device__ __forceinline__ void coh_st64(void* p, u64 v) {
    __hip_atomic_store((u64*)p, v, __ATOMIC_RELAXED, __HIP_MEMORY_SCOPE_AGENT);
}

__device__ __forceinline__ bool flag_ge(const int* f, int idx, int tgt) {
    return __hip_atomic_load(f + idx, __ATOMIC_RELAXED, __HIP_MEMORY_SCOPE_AGENT) >= tgt;
}

// Init: x fp32 -> bf16, initial h -> ring slot 7 (both layers), flags = 0.
__global__ void k_init(const float* __restrict__ x, const float* __restrict__ h,
                       u16* __restrict__ xb, u16* __restrict__ h0ring, u16* __restrict__ h1ring,
                       int* __restrict__ flags0, int* __restrict__ flags1) {
    long i = (long)blockIdx.x * 256 + threadIdx.x;
    if (i < 2097152) {                          // x: 16,777,216 floats, 8 per thread
        const float* p = x + i * 8;
        float4 a = *(const float4*)p;
        float4 b = *(const float4*)(p + 4);
        union { u16 s[8]; bf16x8 v; } u;
        u.s[0]=f2b(a.x); u.s[1]=f2b(a.y); u.s[2]=f2b(a.z); u.s[3]=f2b(a.w);
        u.s[4]=f2b(b.x); u.s[5]=f2b(b.y); u.s[6]=f2b(b.z); u.s[7]=f2b(b.w);
        *(bf16x8*)(xb + i * 8) = u.v;
    } else if (i < 2097152 + 8192) {            // h: [2][64][512] = 65536 floats
        long j = i - 2097152;
        const float* p = h + j * 8;
        #pragma unroll
        for (int jj = 0; jj < 8; ++jj) {
            long idx = j * 8 + jj;
            u16 v = f2b(p[jj]);
            if (idx < 32768) h0ring[7 * 32768 + idx] = v;
            else             h1ring[7 * 32768 + (idx - 32768)] = v;
        }
    } else if (i < 2097152 + 8192 + 512) {      // flags
        int j = (int)(i - (2097152 + 8192));
        if (j < 256) flags0[j] = 0; else flags1[j - 256] = 0;
    }
}

__global__ __launch_bounds__(NTHR, 1) void k_lstm(
    const u16* __restrict__ xb,
    const float* __restrict__ Wx0, const float* __restrict__ Wh0, const float* __restrict__ b0,
    const float* __restrict__ Wx1, const float* __restrict__ Wh1, const float* __restrict__ b1,
    const float* __restrict__ c_in,
    u16* __restrict__ h0ring, u16* __restrict__ h1ring,
    int* __restrict__ flags0, int* __restrict__ flags1,
    float* __restrict__ cs,
    float* __restrict__ out)
{
    const int tid  = threadIdx.x;
    const int bid  = blockIdx.x;
    const int lay  = bid >> 6;        // 0 or 1
    const int g    = (bid >> 4) & 3;  // row group: batch rows [16g, 16g+16)
    const int u    = bid & 15;        // unit block: hidden units [32u, 32u+32)
    const int wave = tid >> 6;
    const int lane = tid & 63;
    const int n    = lane & 15;       // A row-in-tile / B col-in-tile
    const int quad = lane >> 4;
    const int R0   = g * 16;
    const int U0   = u * 32;

    // h staging: flat [buf][row*512 + swz(unit)*8 + sub] u16, XOR-swizzled so
    // both the coalesced ds_write_b64 (consecutive slots) and the MFMA
    // ds_read_b128 (lane (q,n) reads row n, unit f*4+q) are 2-way (free).
    __shared__ __align__(16) u16   hstage[2][8192];      // 32 KiB
    __shared__ __align__(16) u16   sc_all[16 * 36];      // publish tile, 72B/row stride
    __shared__ __align__(16) float sc_h [4][16][8];      // per-wave f32 scratch (out)

    const float* Wx = lay ? Wx1 : Wx0;
    const float* Wh = lay ? Wh1 : Wh0;
    const float* bb = lay ? b1  : b0;
    const float bi = bb[0] + bb[1];
    const float bf = bb[2] + bb[3];
    const float bg = bb[4] + bb[5];
    const float bo = bb[6] + bb[7];

    // ---- Preload this wave's full weight panel into registers (64 frags, 256 VGPR).
    // breg[ct][f]: frag for col-tile ct, K-window f*32..+32 (K<512: Wx, else Wh).
    // Frag layout: lane holds B[k = f*32 + quad*8 + j][col = ct*16 + n].
    bf16x8 breg[2][32];
    #pragma unroll
    for (int ct = 0; ct < 2; ++ct) {
        const int gate = ct * 2 + (n >> 3);            // 0:i 1:f 2:g 3:o
        const int gcol = gate * 512 + U0 + wave * 8 + (n & 7);
        #pragma unroll
        for (int f = 0; f < 32; ++f) {
            const int kbase = f * 32 + quad * 8;
            bf16x8 w;
            #pragma unroll
            for (int j = 0; j < 8; ++j) {
                const int k = kbase + j;
                const float v = (k < 512) ? Wx[(size_t)k * 2048 + gcol]
                                          : Wh[(size_t)(k - 512) * 2048 + gcol];
                w[j] = (short)f2b(v);
            }
            breg[ct][f] = w;
        }
    }

    int* myflag = (lay ? flags1 : flags0) + g * 16 + u;
    const int fidx = g * 16 + n;            // poll: only this row-group's 16 peers
    (void)cs;

    // c-state in registers: lane (n<8, quad) owns local rows quad*4+r, unit U0+wave*8+n.
    float creg[4];
    if (n < 8) {
        #pragma unroll
        for (int r = 0; r < 4; ++r)
            creg[r] = c_in[(size_t)lay * 32768
                           + (size_t)(R0 + quad * 4 + r) * 512 + U0 + wave * 8 + n];
    }

    for (int t = 0; t < 512; ++t) {
        f32x4 acc0 = {0.f, 0.f, 0.f, 0.f};
        f32x4 acc1 = {0.f, 0.f, 0.f, 0.f};

        if (lay == 0) {
            // ---- x-phase: no cross-block dependency; runs before the wait ----
            const u16* px = xb + ((size_t)(R0 + n) * T_ + t) * I_;
            bf16x8 xa[16];
            #pragma unroll
            for (int f = 0; f < 16; ++f) xa[f] = *(const bf16x8*)(px + f * 32 + quad * 8);
            #pragma unroll
            for (int f = 0; f < 16; ++f) {
                acc0 = MFMA(xa[f], breg[0][f], acc0);
                acc1 = MFMA(xa[f], breg[1][f], acc1);
            }
            // ---- wait for own row-group's h0[t-1]; ring WAR check every 4th step ----
            const bool bp = (t & 3) == 0;
            for (;;) {
                bool ok = flag_ge(flags0, fidx, t);
                if (bp) ok = ok && flag_ge(flags1, fidx, t - 4);
                if (__all(ok)) break;
                __builtin_amdgcn_s_sleep(1);
            }
            asm volatile("" ::: "memory");
            // ---- coalesced stage: u64 slot s = i*256+tid; wave instr = 512B contiguous ----
            const u16* base = h0ring + (size_t)((t - 1) & 7) * 32768;
            u64 v[8];
            #pragma unroll
            for (int i = 0; i < 8; ++i) {
                const int s = i * 256 + tid;
                const int r = s >> 7, m = s & 127;
                v[i] = coh_ld64(base + (size_t)(R0 + r) * 512 + m * 4);
            }
            #pragma unroll
            for (int i = 0; i < 8; ++i) {
                const int s = i * 256 + tid;
                const int r = s >> 7, m = s & 127;
                const int uu = m >> 1, sub = m & 1;
                *(u64*)&hstage[0][r * 512 + (((uu ^ (r & 7)) << 3) | (sub << 2))] = v[i];
            }
            __syncthreads();
            #pragma unroll
            for (int f = 0; f < 16; ++f) {
                bf16x8 ha = *(const bf16x8*)
                    &hstage[0][n * 512 + (((f * 4 + quad) ^ (n & 7)) << 3)];
                acc0 = MFMA(ha, breg[0][16 + f], acc0);
                acc1 = MFMA(ha, breg[1][16 + f], acc1);
            }
        } else {
            // ---- wait for h1[t-1] (own layer) AND h0[t] (L0 runs ahead) together ----
            for (;;) {
                bool ok = flag_ge(flags1, fidx, t) && flag_ge(flags0, fidx, t + 1);
                if (__all(ok)) break;
                __builtin_amdgcn_s_sleep(1);
            }
            asm volatile("" ::: "memory");
            const u16* base0 = h0ring + (size_t)(t & 7) * 32768;
            const u16* base1 = h1ring + (size_t)((t - 1) & 7) * 32768;
            u64 v0[8], v1[8];
            #pragma unroll
            for (int i = 0; i < 8; ++i) {
                const int s = i * 256 + tid;
                const int r = s >> 7, m = s & 127;
                v0[i] = coh_ld64(base0 + (size_t)(R0 + r) * 512 + m * 4);
                v1[i] = coh_ld64(base1 + (size_t)(R0 + r) * 512 + m * 4);
            }
            #pragma unroll
            for (int i = 0; i < 8; ++i) {
                const int s = i * 256 + tid;
                const int r = s >> 7, m = s & 127;
                const int uu = m >> 1, sub = m & 1;
                const int off = r * 512 + (((uu ^ (r & 7)) << 3) | (sub << 2));
                *(u64*)&hstage[0][off] = v0[i];
                *(u64*)&hstage[1][off] = v1[i];
            }
            __syncthreads();
            #pragma unroll
            for (int f = 0; f < 16; ++f) {
                const int off = n * 512 + (((f * 4 + quad) ^ (n & 7)) << 3);
                bf16x8 ha = *(const bf16x8*)&hstage[0][off];
                acc0 = MFMA(ha, breg[0][f], acc0);
                acc1 = MFMA(ha, breg[1][f], acc1);
                bf16x8 hb = *(const bf16x8*)&hstage[1][off];
                acc0 = MFMA(hb, breg[0][16 + f], acc0);
                acc1 = MFMA(hb, breg[1][16 + f], acc1);
            }
        }

        // D layout: col = lane&15, row = quad*4 + reg (local rows 0..15).
        // acc0 cols: n<8 -> gate i (unit n), n>=8 -> gate f (unit n-8)
        // acc1 cols: n<8 -> gate g,          n>=8 -> gate o
        f32x4 x0, x1;
        #pragma unroll
        for (int r = 0; r < 4; ++r) {
            x0[r] = __shfl_xor(acc0[r], 8);   // lane n gets zf
            x1[r] = __shfl_xor(acc1[r], 8);   // lane n gets zo
        }
        if (n < 8) {
            #pragma unroll
            for (int r = 0; r < 4; ++r) {
                const int row = quad * 4 + r;
                const float zi = acc0[r] + bi;
                const float zf = x0[r]   + bf;
                const float zg = acc1[r] + bg;
                const float zo = x1[r]   + bo;
                const float ig = 1.f / (1.f + __expf(-zi));
                const float fg = 1.f / (1.f + __expf(-zf));
                const float gg = tanhf(zg);
                const float og = 1.f / (1.f + __expf(-zo));
                const float cn = fg * creg[r] + ig * gg;
                const float hn = og * tanhf(cn);
                creg[r] = cn;
                sc_all[row * 36 + wave * 8 + n] = f2b(hn);
                sc_h [wave][row][n] = hn;
            }
        }
        __syncthreads();   // all waves' sc_all columns in place

        // ---- coalesced publish by wave 0 only: 16 rows x 64B as 2 u64-instrs ----
        // (consecutive lanes -> consecutive addresses; 64B granules per row)
        if (wave == 0) {
            u16* ring = (lay ? h1ring : h0ring) + (size_t)(t & 7) * 32768;
            #pragma unroll
            for (int k = 0; k < 2; ++k) {
                const int j   = k * 64 + lane;
                const int row = j >> 3, s8 = j & 7;
                u64 vv = *(const u64*)&sc_all[row * 36 + s8 * 4];
                coh_st64(ring + (size_t)(R0 + row) * 512 + U0 + s8 * 4, vv);
            }
            asm volatile("s_waitcnt vmcnt(0)" ::: "memory");  // h at coherence point
            if (lane == 0)
                __hip_atomic_store(myflag, t + 1, __ATOMIC_RELAXED, __HIP_MEMORY_SCOPE_AGENT);
        }
        // NOTE: no barrier needed here — peers (and our own next step) gate on
        // myflag, which is set only after sc_all/hstage are fully consumed.

        // ---- off-critical-path outputs (drain folds into next step's waits) ----
        if (lay && lane < 16) {
            const float* s = &sc_h[wave][lane][0];
            f32x4 a  = *(const f32x4*)s;
            f32x4 b2 = *(const f32x4*)(s + 4);
            float* po = out + ((size_t)(R0 + lane) * T_ + t) * H_ + U0 + wave * 8;
            *(f32x4*)po       = a;
            *(f32x4*)(po + 4) = b2;
        }
        if (t == 511 && n < 8) {
            const size_t o1 = (size_t)B_ * T_ * H_;   // 16,777,216
            #pragma unroll
            for (int r = 0; r < 4; ++r) {
                const int grow = R0 + quad * 4 + r;
                out[o1 +         (size_t)lay * 32768 + (size_t)grow * 512 + U0 + wave * 8 + n]
                    = sc_h[wave][quad * 4 + r][n];
                out[o1 + 65536 + (size_t)lay * 32768 + (size_t)grow * 512 + U0 + wave * 8 + n]
                    = creg[r];
            }
        }
    }
}

extern "C" void kernel_launch(void* const* d_in, const int* in_sizes, int n_in,
                              void* d_out, int out_size, void* d_ws, size_t ws_size,
                              hipStream_t stream) {
    const float* x   = (const float*)d_in[0];
    const float* h   = (const float*)d_in[1];
    const float* c   = (const float*)d_in[2];
    const float* Wx0 = (const float*)d_in[3];
    const float* Wh0 = (const float*)d_in[4];
    const float* b0  = (const float*)d_in[5];
    const float* Wx1 = (const float*)d_in[6];
    const float* Wh1 = (const float*)d_in[7];
    const float* b1  = (const float*)d_in[8];
    float* out = (float*)d_out;

    // ws layout (~35 MB): xb bf16, h rings (depth 8, bf16), flags, spare.
    u16* xb     = (u16*)d_ws;                 // 16,777,216 u16
    u16* h0ring = xb + 16777216;              // 8*32768 u16
    u16* h1ring = h0ring + 262144;            // 8*32768 u16
    int* flags0 = (int*)(h1ring + 262144);    // 256 ints (only [0,64) used)
    int* flags1 = flags0 + 256;               // 256 ints (only [0,64) used)
    float* cs   = (float*)(flags1 + 256);     // spare (unused)

    k_init<<<8226, 256, 0, stream>>>(x, h, xb, h0ring, h1ring, flags0, flags1);
    k_lstm<<<NBLK, NTHR, 0, stream>>>(xb, Wx0, Wh0, b0, Wx1, Wh1, b1, c,
                                      h0ring, h1ring, flags0, flags1, cs, out);
}

// Round 6
// 2938.356 us; speedup vs baseline: 2.6727x; 1.0679x over previous
//
#include <hip/hip_runtime.h>
#include <hip/hip_bf16.h>

// Sizes (fixed by the problem)
#define B_   64
#define T_   512
#define I_   512
#define H_   512
#define NTHR 256   // 4 waves; wave w owns units [U0+8w, U0+8w+8), all 16 rows

typedef short bf16x8 __attribute__((ext_vector_type(8)));
typedef float f32x4  __attribute__((ext_vector_type(4)));
typedef unsigned long long u64;
typedef unsigned short u16;

#define MFMA(a, b, c) __builtin_amdgcn_mfma_f32_16x16x32_bf16((a), (b), (c), 0, 0, 0)

__device__ __forceinline__ u16 f2b(float f) {
    __hip_bfloat16 h = __float2bfloat16(f);   // RNE
    return __builtin_bit_cast(u16, h);
}

// ---- agent-scope (LLC) ops: fallback path + consensus/verdict exchange ----
__device__ __forceinline__ u64 coh_ld64(const void* p) {
    return __hip_atomic_load((const u64*)p, __ATOMIC_RELAXED, __HIP_MEMORY_SCOPE_AGENT);
}
__device__ __forceinline__ void coh_st64(void* p, u64 v) {
    __hip_atomic_store((u64*)p, v, __ATOMIC_RELAXED, __HIP_MEMORY_SCOPE_AGENT);
}
__device__ __forceinline__ bool flag_ge(const int* f, int idx, int tgt) {
    return __hip_atomic_load(f + idx, __ATOMIC_RELAXED, __HIP_MEMORY_SCOPE_AGENT) >= tgt;
}

// ---- XCD-local (sc0 = L1-bypass, served by the XCD's shared L2) ----
__device__ __forceinline__ int sc0_ld_i32(const int* p) {
    int v;
    asm volatile("global_load_dword %0, %1, off sc0\n\ts_waitcnt vmcnt(0)"
                 : "=&v"(v) : "v"(p) : "memory");
    return v;
}
__device__ __forceinline__ void sc0_st_i32(int* p, int v) {
    asm volatile("global_store_dword %0, %1, off sc0" :: "v"(p), "v"(v) : "memory");
}

// batched XCD-local fragment load: 16x dwordx4 sc0, waited inside (no rule-18 hazard)
#define GLD16(O, A)                                                         \
  asm volatile(                                                             \
    "global_load_dwordx4 %0, %16, off sc0\n\t"                              \
    "global_load_dwordx4 %1, %16, off offset:64 sc0\n\t"                    \
    "global_load_dwordx4 %2, %16, off offset:128 sc0\n\t"                   \
    "global_load_dwordx4 %3, %16, off offset:192 sc0\n\t"                   \
    "global_load_dwordx4 %4, %16, off offset:256 sc0\n\t"                   \
    "global_load_dwordx4 %5, %16, off offset:320 sc0\n\t"                   \
    "global_load_dwordx4 %6, %16, off offset:384 sc0\n\t"                   \
    "global_load_dwordx4 %7, %16, off offset:448 sc0\n\t"                   \
    "global_load_dwordx4 %8, %16, off offset:512 sc0\n\t"                   \
    "global_load_dwordx4 %9, %16, off offset:576 sc0\n\t"                   \
    "global_load_dwordx4 %10, %16, off offset:640 sc0\n\t"                  \
    "global_load_dwordx4 %11, %16, off offset:704 sc0\n\t"                  \
    "global_load_dwordx4 %12, %16, off offset:768 sc0\n\t"                  \
    "global_load_dwordx4 %13, %16, off offset:832 sc0\n\t"                  \
    "global_load_dwordx4 %14, %16, off offset:896 sc0\n\t"                  \
    "global_load_dwordx4 %15, %16, off offset:960 sc0\n\t"                  \
    "s_waitcnt vmcnt(0)"                                                    \
    : "=&v"(O[0]), "=&v"(O[1]), "=&v"(O[2]), "=&v"(O[3]),                   \
      "=&v"(O[4]), "=&v"(O[5]), "=&v"(O[6]), "=&v"(O[7]),                   \
      "=&v"(O[8]), "=&v"(O[9]), "=&v"(O[10]), "=&v"(O[11]),                 \
      "=&v"(O[12]), "=&v"(O[13]), "=&v"(O[14]), "=&v"(O[15])                \
    : "v"(A) : "memory")

// XCD-local publish: block tile (16 rows x 64B) from sc_all, then flag.
__device__ __forceinline__ void pub_local(u16* ring, int* fp, int fval,
                                          const u16* sca, int lane, int U0) {
    const int r0 = lane >> 3, s0 = lane & 7;
    const int r1 = 8 + r0;
    u64 q0 = *(const u64*)(sca + r0 * 36 + s0 * 4);
    u64 q1 = *(const u64*)(sca + r1 * 36 + s0 * 4);
    u16* d0 = ring + r0 * 512 + U0 + s0 * 4;
    u16* d1 = ring + r1 * 512 + U0 + s0 * 4;
    asm volatile(
        "global_store_dwordx2 %0, %2, off sc0\n\t"
        "global_store_dwordx2 %1, %3, off sc0\n\t"
        "s_waitcnt vmcnt(0)"
        :: "v"(d0), "v"(d1), "v"(q0), "v"(q1) : "memory");
    if (lane == 0) sc0_st_i32(fp, fval);
}

// Agent publish (fallback): same tile into [64][512] ring at global rows.
__device__ __forceinline__ void pub_agent(u16* ring, int* fp, int fval,
                                          const u16* sca, int lane, int R0, int U0) {
    const int r0 = lane >> 3, s0 = lane & 7;
    const int r1 = 8 + r0;
    u64 q0 = *(const u64*)(sca + r0 * 36 + s0 * 4);
    u64 q1 = *(const u64*)(sca + r1 * 36 + s0 * 4);
    coh_st64(ring + (size_t)(R0 + r0) * 512 + U0 + s0 * 4, q0);
    coh_st64(ring + (size_t)(R0 + r1) * 512 + U0 + s0 * 4, q1);
    asm volatile("s_waitcnt vmcnt(0)" ::: "memory");
    if (lane == 0)
        __hip_atomic_store(fp, fval, __ATOMIC_RELAXED, __HIP_MEMORY_SCOPE_AGENT);
}

// Init: x fp32 -> bf16; all 1024 control ints = -1. (h published in-kernel.)
__global__ void k_init(const float* __restrict__ x, u16* __restrict__ xb,
                       int* __restrict__ fl) {
    long i = (long)blockIdx.x * 256 + threadIdx.x;
    if (i < 2097152) {
        const float* p = x + i * 8;
        float4 a = *(const float4*)p;
        float4 b = *(const float4*)(p + 4);
        union { u16 s[8]; bf16x8 v; } u;
        u.s[0]=f2b(a.x); u.s[1]=f2b(a.y); u.s[2]=f2b(a.z); u.s[3]=f2b(a.w);
        u.s[4]=f2b(b.x); u.s[5]=f2b(b.y); u.s[6]=f2b(b.z); u.s[7]=f2b(b.w);
        *(bf16x8*)(xb + i * 8) = u.v;
    } else if (i < 2097152 + 1024) {
        fl[i - 2097152] = -1;
    }
}

__global__ __launch_bounds__(NTHR, 1) void k_lstm(
    const u16* __restrict__ xb,
    const float* __restrict__ Wx0, const float* __restrict__ Wh0, const float* __restrict__ b0,
    const float* __restrict__ Wx1, const float* __restrict__ Wh1, const float* __restrict__ b1,
    const float* __restrict__ c_in, const float* __restrict__ h_in,
    u16* __restrict__ h0ag, u16* __restrict__ h1ag,
    u16* __restrict__ h0loc, u16* __restrict__ h1loc,
    int* __restrict__ f0ag, int* __restrict__ f1ag,
    int* __restrict__ f0loc, int* __restrict__ f1loc,
    int* __restrict__ xcc_tab, int* __restrict__ probe, int* __restrict__ verd,
    float* __restrict__ out)
{
    const int bid = blockIdx.x;
    if ((bid & 7) >= 4) return;       // dummy blocks (XCD padding) exit
    const int g   = bid & 7;          // row group 0..3 -> target XCD g
    const int jj  = bid >> 3;         // 0..31
    const int lay = jj >> 4;          // 0/1
    const int u   = jj & 15;          // unit block: units [32u, 32u+32)
    const int tid  = threadIdx.x;
    const int wave = tid >> 6;
    const int lane = tid & 63;
    const int n    = lane & 15;
    const int quad = lane >> 4;
    const int R0   = g * 16;
    const int U0   = u * 32;

    __shared__ __align__(16) u16   hstage[2][8192];      // fallback staging
    __shared__ __align__(16) u16   sc_all[16 * 36];      // publish tile
    __shared__ __align__(16) float sc_h [4][16][8];
    __shared__ int s_local;
    __shared__ int s_ver;

    // publish own XCC id (agent) for placement consensus
    int myxcc;
    asm volatile("s_getreg_b32 %0, hwreg(HW_REG_XCC_ID)" : "=s"(myxcc));
    if (tid == 0)
        __hip_atomic_store(xcc_tab + bid, myxcc, __ATOMIC_RELAXED, __HIP_MEMORY_SCOPE_AGENT);

    const float* Wx = lay ? Wx1 : Wx0;
    const float* Wh = lay ? Wh1 : Wh0;
    const float* bb = lay ? b1  : b0;
    const float bi = bb[0] + bb[1];
    const float bf = bb[2] + bb[3];
    const float bg = bb[4] + bb[5];
    const float bo = bb[6] + bb[7];

    // Full weight panel in registers (64 frags).
    // breg[ct][f]: lane holds B[k = f*32 + quad*8 + j][col = ct*16 + n]; k<512: Wx else Wh.
    bf16x8 breg[2][32];
    #pragma unroll
    for (int ct = 0; ct < 2; ++ct) {
        const int gate = ct * 2 + (n >> 3);            // 0:i 1:f 2:g 3:o
        const int gcol = gate * 512 + U0 + wave * 8 + (n & 7);
        #pragma unroll
        for (int f = 0; f < 32; ++f) {
            const int kbase = f * 32 + quad * 8;
            bf16x8 w;
            #pragma unroll
            for (int j = 0; j < 8; ++j) {
                const int k = kbase + j;
                const float v = (k < 512) ? Wx[(size_t)k * 2048 + gcol]
                                          : Wh[(size_t)(k - 512) * 2048 + gcol];
                w[j] = (short)f2b(v);
            }
            breg[ct][f] = w;
        }
    }

    // c-state in registers
    float creg[4];
    if (n < 8) {
        #pragma unroll
        for (int r = 0; r < 4; ++r)
            creg[r] = c_in[(size_t)lay * 32768
                           + (size_t)(R0 + quad * 4 + r) * 512 + U0 + wave * 8 + n];
    }

    // ---- stage 1: XCC consensus (are all 32 group members on one XCD?) ----
    if (wave == 0) {
        const int member = (lane & 31) * 8 + g;
        int v;
        for (;;) {
            v = __hip_atomic_load(xcc_tab + member, __ATOMIC_RELAXED, __HIP_MEMORY_SCOPE_AGENT);
            if (__all(v != -1)) break;
            __builtin_amdgcn_s_sleep(8);
        }
        const int v0 = __shfl(v, 0);
        if (lane == 0) s_local = __all(v == v0) ? 1 : 0;
    }
    __syncthreads();

    // ---- stage 2: bounded sc0 coherence probe (only if consensus passed) ----
    int myver = 0;
    if (s_local) {                       // block-uniform
        if (tid == 0) sc0_st_i32(probe + bid, 0x5a5a0000 | bid);
        if (wave == 0) {
            const int member = (lane & 31) * 8 + g;
            const int want = 0x5a5a0000 | member;
            int ok = 0;
            for (int it = 0; it < 4000 && !ok; ++it)
                ok = __all(sc0_ld_i32(probe + member) == want) ? 1 : 0;
            if (lane == 0) s_ver = ok;
        }
        __syncthreads();
        myver = s_ver;
    }

    // ---- stage 3: verdict exchange over the PROVEN agent path; AND-combine ----
    if (tid == 0)
        __hip_atomic_store(verd + bid, myver, __ATOMIC_RELAXED, __HIP_MEMORY_SCOPE_AGENT);
    if (wave == 0) {
        const int member = (lane & 31) * 8 + g;
        int v;
        for (;;) {
            v = __hip_atomic_load(verd + member, __ATOMIC_RELAXED, __HIP_MEMORY_SCOPE_AGENT);
            if (__all(v != -1)) break;
            __builtin_amdgcn_s_sleep(8);
        }
        if (lane == 0) s_local = __all(v == 1) ? 1 : 0;
    }
    __syncthreads();
    const bool loc = (s_local != 0);     // group-uniform by construction

    // ---- prologue: publish initial h as "step -1" (slot 7), flag = 0 ----
    if (n < 8) {
        #pragma unroll
        for (int r = 0; r < 4; ++r) {
            const int row = quad * 4 + r;
            const float hv = h_in[(size_t)lay * 32768
                                  + (size_t)(R0 + row) * 512 + U0 + wave * 8 + n];
            sc_all[row * 36 + wave * 8 + n] = f2b(hv);
        }
    }
    __syncthreads();
    if (loc) {
        if (wave == 3)   // (t=-1)&3
            pub_local((lay ? h1loc : h0loc) + (size_t)g * 65536 + 7 * 8192,
                      (lay ? f1loc : f0loc) + g * 16 + u, 0, sc_all, lane, U0);
    } else {
        if (wave == 0)
            pub_agent((lay ? h1ag : h0ag) + (size_t)7 * 32768,
                      (lay ? f1ag : f0ag) + g * 16 + u, 0, sc_all, lane, R0, U0);
    }

    const int fidx = g * 16 + n;

    if (loc) {
        // =================== XCD-LOCAL PATH ===================
        int* pp0 = f0loc + g * 16 + n;
        int* pp1 = f1loc + g * 16 + n;
        if (lay == 0) {
            for (int t = 0; t < 512; ++t) {
                f32x4 acc0 = {0.f,0.f,0.f,0.f}, acc1 = {0.f,0.f,0.f,0.f};
                // x-phase before the wait
                const u16* px = xb + ((size_t)(R0 + n) * T_ + t) * I_;
                bf16x8 xa[16];
                #pragma unroll
                for (int f = 0; f < 16; ++f) xa[f] = *(const bf16x8*)(px + f * 32 + quad * 8);
                #pragma unroll
                for (int f = 0; f < 16; ++f) {
                    acc0 = MFMA(xa[f], breg[0][f], acc0);
                    acc1 = MFMA(xa[f], breg[1][f], acc1);
                }
                // poll peers (local L2); every 4th step add L1 WAR back-pressure
                if ((t & 3) == 0) {
                    for (;;) {
                        int a_ = sc0_ld_i32(pp0);
                        int b_ = sc0_ld_i32(pp1);
                        if (__all(a_ >= t && b_ >= t - 4)) break;
                    }
                } else {
                    while (!__all(sc0_ld_i32(pp0) >= t)) {}
                }
                // direct per-lane fragment loads from local ring (L2-served)
                const u16* ha = h0loc + (size_t)g * 65536
                                + (size_t)((t - 1) & 7) * 8192 + n * 512 + quad * 8;
                bf16x8 hf[16];
                GLD16(hf, ha);
                #pragma unroll
                for (int f = 0; f < 16; ++f) {
                    acc0 = MFMA(hf[f], breg[0][16 + f], acc0);
                    acc1 = MFMA(hf[f], breg[1][16 + f], acc1);
                }
                // epilogue
                f32x4 x0, x1;
                #pragma unroll
                for (int r = 0; r < 4; ++r) {
                    x0[r] = __shfl_xor(acc0[r], 8);
                    x1[r] = __shfl_xor(acc1[r], 8);
                }
                if (n < 8) {
                    #pragma unroll
                    for (int r = 0; r < 4; ++r) {
                        const int row = quad * 4 + r;
                        const float zi = acc0[r] + bi, zf = x0[r] + bf;
                        const float zg = acc1[r] + bg, zo = x1[r] + bo;
                        const float ig = 1.f / (1.f + __expf(-zi));
                        const float fg = 1.f / (1.f + __expf(-zf));
                        const float gg = tanhf(zg);
                        const float og = 1.f / (1.f + __expf(-zo));
                        const float cn = fg * creg[r] + ig * gg;
                        const float hn = og * tanhf(cn);
                        creg[r] = cn;
                        sc_all[row * 36 + wave * 8 + n] = f2b(hn);
                        sc_h[wave][row][n] = hn;
                    }
                }
                __syncthreads();
                if (wave == (t & 3))
                    pub_local(h0loc + (size_t)g * 65536 + (size_t)(t & 7) * 8192,
                              f0loc + g * 16 + u, t + 1, sc_all, lane, U0);
                if (t == 511 && n < 8) {
                    const size_t o1 = (size_t)B_ * T_ * H_;
                    #pragma unroll
                    for (int r = 0; r < 4; ++r) {
                        const int grow = R0 + quad * 4 + r;
                        out[o1 + (size_t)grow * 512 + U0 + wave * 8 + n]
                            = sc_h[wave][quad * 4 + r][n];
                        out[o1 + 65536 + (size_t)grow * 512 + U0 + wave * 8 + n] = creg[r];
                    }
                }
            }
        } else {
            for (int t = 0; t < 512; ++t) {
                // poll h1[t-1] (peers) AND h0[t] (L0, same XCD)
                for (;;) {
                    int a_ = sc0_ld_i32(pp1);
                    int b_ = sc0_ld_i32(pp0);
                    if (__all(a_ >= t && b_ >= t + 1)) break;
                }
                const u16* a0p = h0loc + (size_t)g * 65536
                                 + (size_t)(t & 7) * 8192 + n * 512 + quad * 8;
                const u16* a1p = h1loc + (size_t)g * 65536
                                 + (size_t)((t - 1) & 7) * 8192 + n * 512 + quad * 8;
                f32x4 acc0 = {0.f,0.f,0.f,0.f}, acc1 = {0.f,0.f,0.f,0.f};
                bf16x8 hf[16];
                GLD16(hf, a0p);
                #pragma unroll
                for (int f = 0; f < 16; ++f) {
                    acc0 = MFMA(hf[f], breg[0][f], acc0);
                    acc1 = MFMA(hf[f], breg[1][f], acc1);
                }
                GLD16(hf, a1p);
                #pragma unroll
                for (int f = 0; f < 16; ++f) {
                    acc0 = MFMA(hf[f], breg[0][16 + f], acc0);
                    acc1 = MFMA(hf[f], breg[1][16 + f], acc1);
                }
                f32x4 x0, x1;
                #pragma unroll
                for (int r = 0; r < 4; ++r) {
                    x0[r] = __shfl_xor(acc0[r], 8);
                    x1[r] = __shfl_xor(acc1[r], 8);
                }
                if (n < 8) {
                    #pragma unroll
                    for (int r = 0; r < 4; ++r) {
                        const int row = quad * 4 + r;
                        const float zi = acc0[r] + bi, zf = x0[r] + bf;
                        const float zg = acc1[r] + bg, zo = x1[r] + bo;
                        const float ig = 1.f / (1.f + __expf(-zi));
                        const float fg = 1.f / (1.f + __expf(-zf));
                        const float gg = tanhf(zg);
                        const float og = 1.f / (1.f + __expf(-zo));
                        const float cn = fg * creg[r] + ig * gg;
                        const float hn = og * tanhf(cn);
                        creg[r] = cn;
                        sc_all[row * 36 + wave * 8 + n] = f2b(hn);
                        sc_h[wave][row][n] = hn;
                    }
                }
                __syncthreads();
                if (wave == (t & 3))
                    pub_local(h1loc + (size_t)g * 65536 + (size_t)(t & 7) * 8192,
                              f1loc + g * 16 + u, t + 1, sc_all, lane, U0);
                if (lane < 16) {
                    const float* s = &sc_h[wave][lane][0];
                    f32x4 a  = *(const f32x4*)s;
                    f32x4 b2 = *(const f32x4*)(s + 4);
                    float* po = out + ((size_t)(R0 + lane) * T_ + t) * H_ + U0 + wave * 8;
                    *(f32x4*)po       = a;
                    *(f32x4*)(po + 4) = b2;
                }
                if (t == 511 && n < 8) {
                    const size_t o1 = (size_t)B_ * T_ * H_;
                    #pragma unroll
                    for (int r = 0; r < 4; ++r) {
                        const int grow = R0 + quad * 4 + r;
                        out[o1 + 32768 + (size_t)grow * 512 + U0 + wave * 8 + n]
                            = sc_h[wave][quad * 4 + r][n];
                        out[o1 + 65536 + 32768 + (size_t)grow * 512 + U0 + wave * 8 + n]
                            = creg[r];
                    }
                }
            }
        }
        return;
    }

    // =================== FALLBACK: agent path (R4, proven) ===================
    for (int t = 0; t < 512; ++t) {
        f32x4 acc0 = {0.f,0.f,0.f,0.f}, acc1 = {0.f,0.f,0.f,0.f};
        if (lay == 0) {
            const u16* px = xb + ((size_t)(R0 + n) * T_ + t) * I_;
            bf16x8 xa[16];
            #pragma unroll
            for (int f = 0; f < 16; ++f) xa[f] = *(const bf16x8*)(px + f * 32 + quad * 8);
            #pragma unroll
            for (int f = 0; f < 16; ++f) {
                acc0 = MFMA(xa[f], breg[0][f], acc0);
                acc1 = MFMA(xa[f], breg[1][f], acc1);
            }
            const bool bp = (t & 3) == 0;
            for (;;) {
                bool ok = flag_ge(f0ag, fidx, t);
                if (bp) ok = ok && flag_ge(f1ag, fidx, t - 4);
                if (__all(ok)) break;
                __builtin_amdgcn_s_sleep(1);
            }
            asm volatile("" ::: "memory");
            const u16* base = h0ag + (size_t)((t - 1) & 7) * 32768;
            u64 v[8];
            #pragma unroll
            for (int i = 0; i < 8; ++i) {
                const int s = i * 256 + tid;
                const int r = s >> 7, m = s & 127;
                v[i] = coh_ld64(base + (size_t)(R0 + r) * 512 + m * 4);
            }
            #pragma unroll
            for (int i = 0; i < 8; ++i) {
                const int s = i * 256 + tid;
                const int r = s >> 7, m = s & 127;
                const int uu = m >> 1, sub = m & 1;
                *(u64*)&hstage[0][r * 512 + (((uu ^ (r & 7)) << 3) | (sub << 2))] = v[i];
            }
            __syncthreads();
            #pragma unroll
            for (int f = 0; f < 16; ++f) {
                bf16x8 ha = *(const bf16x8*)
                    &hstage[0][n * 512 + (((f * 4 + quad) ^ (n & 7)) << 3)];
                acc0 = MFMA(ha, breg[0][16 + f], acc0);
                acc1 = MFMA(ha, breg[1][16 + f], acc1);
            }
        } else {
            for (;;) {
                bool ok = flag_ge(f1ag, fidx, t) && flag_ge(f0ag, fidx, t + 1);
                if (__all(ok)) break;
                __builtin_amdgcn_s_sleep(1);
            }
            asm volatile("" ::: "memory");
            const u16* base0 = h0ag + (size_t)(t & 7) * 32768;
            const u16* base1 = h1ag + (size_t)((t - 1) & 7) * 32768;
            u64 v0[8], v1[8];
            #pragma unroll
            for (int i = 0; i < 8; ++i) {
                const int s = i * 256 + tid;
                const int r = s >> 7, m = s & 127;
                v0[i] = coh_ld64(base0 + (size_t)(R0 + r) * 512 + m * 4);
                v1[i] = coh_ld64(base1 + (size_t)(R0 + r) * 512 + m * 4);
            }
            #pragma unroll
            for (int i = 0; i < 8; ++i) {
                const int s = i * 256 + tid;
                const int r = s >> 7, m = s & 127;
                const int uu = m >> 1, sub = m & 1;
                const int off = r * 512 + (((uu ^ (r & 7)) << 3) | (sub << 2));
                *(u64*)&hstage[0][off] = v0[i];
                *(u64*)&hstage[1][off] = v1[i];
            }
            __syncthreads();
            #pragma unroll
            for (int f = 0; f < 16; ++f) {
                const int off = n * 512 + (((f * 4 + quad) ^ (n & 7)) << 3);
                bf16x8 ha = *(const bf16x8*)&hstage[0][off];
                acc0 = MFMA(ha, breg[0][f], acc0);
                acc1 = MFMA(ha, breg[1][f], acc1);
                bf16x8 hb = *(const bf16x8*)&hstage[1][off];
                acc0 = MFMA(hb, breg[0][16 + f], acc0);
                acc1 = MFMA(hb, breg[1][16 + f], acc1);
            }
        }
        f32x4 x0, x1;
        #pragma unroll
        for (int r = 0; r < 4; ++r) {
            x0[r] = __shfl_xor(acc0[r], 8);
            x1[r] = __shfl_xor(acc1[r], 8);
        }
        if (n < 8) {
            #pragma unroll
            for (int r = 0; r < 4; ++r) {
                const int row = quad * 4 + r;
                const float zi = acc0[r] + bi, zf = x0[r] + bf;
                const float zg = acc1[r] + bg, zo = x1[r] + bo;
                const float ig = 1.f / (1.f + __expf(-zi));
                const float fg = 1.f / (1.f + __expf(-zf));
                const float gg = tanhf(zg);
                const float og = 1.f / (1.f + __expf(-zo));
                const float cn = fg * creg[r] + ig * gg;
                const float hn = og * tanhf(cn);
                creg[r] = cn;
                sc_all[row * 36 + wave * 8 + n] = f2b(hn);
                sc_h[wave][row][n] = hn;
            }
        }
        __syncthreads();
        if (wave == 0)
            pub_agent((lay ? h1ag : h0ag) + (size_t)(t & 7) * 32768,
                      (lay ? f1ag : f0ag) + g * 16 + u, t + 1, sc_all, lane, R0, U0);
        if (lay && lane < 16) {
            const float* s = &sc_h[wave][lane][0];
            f32x4 a  = *(const f32x4*)s;
            f32x4 b2 = *(const f32x4*)(s + 4);
            float* po = out + ((size_t)(R0 + lane) * T_ + t) * H_ + U0 + wave * 8;
            *(f32x4*)po       = a;
            *(f32x4*)(po + 4) = b2;
        }
        if (t == 511 && n < 8) {
            const size_t o1 = (size_t)B_ * T_ * H_;
            #pragma unroll
            for (int r = 0; r < 4; ++r) {
                const int grow = R0 + quad * 4 + r;
                out[o1 + (size_t)lay * 32768 + (size_t)grow * 512 + U0 + wave * 8 + n]
                    = sc_h[wave][quad * 4 + r][n];
                out[o1 + 65536 + (size_t)lay * 32768 + (size_t)grow * 512 + U0 + wave * 8 + n]
                    = creg[r];
            }
        }
    }
}

extern "C" void kernel_launch(void* const* d_in, const int* in_sizes, int n_in,
                              void* d_out, int out_size, void* d_ws, size_t ws_size,
                              hipStream_t stream) {
    const float* x   = (const float*)d_in[0];
    const float* h   = (const float*)d_in[1];
    const float* c   = (const float*)d_in[2];
    const float* Wx0 = (const float*)d_in[3];
    const float* Wh0 = (const float*)d_in[4];
    const float* b0  = (const float*)d_in[5];
    const float* Wx1 = (const float*)d_in[6];
    const float* Wh1 = (const float*)d_in[7];
    const float* b1  = (const float*)d_in[8];
    float* out = (float*)d_out;

    // ws (~36 MB): xb, agent rings, local rings (4 groups x depth8 x 16 x 512),
    // then 1024 contiguous ints: f0ag|f1ag|f0loc|f1loc|xcc|probe|verd.
    u16* xb     = (u16*)d_ws;                 // 16,777,216 u16
    u16* h0ag   = xb + 16777216;              // 262144 u16
    u16* h1ag   = h0ag + 262144;              // 262144 u16
    u16* h0loc  = h1ag + 262144;              // 262144 u16
    u16* h1loc  = h0loc + 262144;             // 262144 u16
    int* f0ag   = (int*)(h1loc + 262144);     // 64
    int* f1ag   = f0ag + 64;                  // 64
    int* f0loc  = f1ag + 64;                  // 64
    int* f1loc  = f0loc + 64;                 // 64
    int* xcc    = f1loc + 64;                 // 256
    int* probe  = xcc + 256;                  // 256
    int* verd   = probe + 256;                // 256

    k_init<<<8196, 256, 0, stream>>>(x, xb, f0ag);
    k_lstm<<<256, NTHR, 0, stream>>>(xb, Wx0, Wh0, b0, Wx1, Wh1, b1, c, h,
                                     h0ag, h1ag, h0loc, h1loc,
                                     f0ag, f1ag, f0loc, f1loc, xcc, probe, verd, out);
}